// Round 16
// baseline (368.464 us; speedup 1.0000x reference)
//
#include <hip/hip_runtime.h>

// CombinedLoss: 0.7*MSE + 0.3*mean_b softDTW_gamma.  B=64, T=1024, C=8, fp32.
// R23 = R19 machinery at 2 waves/SIMD.  R22 proved F~=0 (K=32 flat) -> cost
// is purely 2048 diag-steps x ~300cy: ~130 issue + ~170 exposed chain stall
// that 7 ILP levers (R10-R19) couldn't fill from within one wave.  The one
// untested lever: TLP.  R8's 8-wave regression was on the BARRIER-STEPPED
// structure (drain swamped SMT); the free-running structure has no per-step
// barriers.  128 blocks x 512 thr: 8 waves/block = 2 waves/SIMD, each wave's
// chain stalls filled by its SIMD-mate's issue.  Wave g=8h+w_ owns rows
// [64g,64g+63]; 7/8 halos intra-block (LDS flags); one cross-block boundary
// per batch (row 512) via the proven self-validating 8B atomic ring
// (kb=448, RING=1088).  Step code identical to R19: dg=up_prev carry,
// 3-buffer D-load rotation, 48B-stride padded columns.
// ws: [0,128) mse | [256,320) sdtw | u64 rings @ float-offset 320 (~560 KB).

constexpr int TT = 1024;
constexpr float ALPHA_ = 0.7f;
constexpr float FINF = 1000000000.0f;
constexpr int RING = 1088;

__device__ __forceinline__ float shflup1(float old0, float v) {
    return __int_as_float(__builtin_amdgcn_update_dpp(
        __float_as_int(old0), __float_as_int(v), 0x138, 0xf, 0xf, false));
}
__device__ __forceinline__ float rotdn1(float v) {
    return __int_as_float(__builtin_amdgcn_update_dpp(
        0, __float_as_int(v), 0x130, 0xf, 0xf, false));
}

__global__ __launch_bounds__(512) void sdtw_band_kernel(
    const float* __restrict__ pred, const float* __restrict__ target,
    float* __restrict__ ws)
{
    // col j: A-half at 3j, B-half at 3j+1, y2 at 3j+2.x (48B stride)
    __shared__ float4 s_c4[TT * 3];
    __shared__ float  s_row[8][1088];    // per-wave bottom row, local diag idx
    __shared__ float  s_red[8];
    __shared__ int    s_prog[8];         // last completed ABS window per wave

    const int blk = blockIdx.x;
    const int b   = blk & 63;                  // batch
    const int h   = blk >> 6;                  // half: rows [512h, 512h+511]
    const int tid = threadIdx.x;
    const int l   = tid & 63;
    const int w_  = __builtin_amdgcn_readfirstlane(tid >> 6);   // 0..7
    const int g   = (h << 3) + w_;             // global wave 0..15
    const int gbase = g << 6;
    const int row   = gbase + l;

    if (tid < 8) s_prog[tid] = -1;

    const float* pr = pred   + ((size_t)b * TT + row) * 8;
    const float* tr = target + ((size_t)b * TT + row) * 8;
    const float4 pa = ((const float4*)pr)[0];
    const float4 pb = ((const float4*)pr)[1];
    const float4 ma = ((const float4*)tr)[0];
    const float4 mb = ((const float4*)tr)[1];

    float x2 = 0.f, msep = 0.f;
    {
        const float pp[8] = {pa.x,pa.y,pa.z,pa.w,pb.x,pb.y,pb.z,pb.w};
        const float tt[8] = {ma.x,ma.y,ma.z,ma.w,mb.x,mb.y,mb.z,mb.w};
        #pragma unroll
        for (int c = 0; c < 8; ++c) {
            x2 = fmaf(pp[c], pp[c], x2);
            float d = pp[c] - tt[c];
            msep = fmaf(d, d, msep);
        }
    }
    // stage all 1024 columns (2 per thread), padded layout
    const float* tg = target + (size_t)b * TT * 8;
    #pragma unroll
    for (int c0 = 0; c0 < 2; ++c0) {
        const int col = tid + (c0 << 9);
        const float4 u0 = ((const float4*)(tg + (size_t)col * 8))[0];
        const float4 u1 = ((const float4*)(tg + (size_t)col * 8))[1];
        const float y2 = u0.x*u0.x + u0.y*u0.y + u0.z*u0.z + u0.w*u0.w
                       + u1.x*u1.x + u1.y*u1.y + u1.z*u1.z + u1.w*u1.w;
        s_c4[3*col]   = make_float4(-2.f*u0.x, -2.f*u0.y, -2.f*u0.z, -2.f*u0.w);
        s_c4[3*col+1] = make_float4(-2.f*u1.x, -2.f*u1.y, -2.f*u1.z, -2.f*u1.w);
        s_c4[3*col+2] = make_float4(y2, 0.f, 0.f, 0.f);
    }
    #pragma unroll
    for (int off = 32; off > 0; off >>= 1) msep += __shfl_down(msep, off, 64);
    if (l == 0) s_red[w_] = msep;
    __syncthreads();                      // the ONLY block-wide barrier
    if (tid == 0) {
        float s0 = 0.f;
        #pragma unroll
        for (int i = 0; i < 8; ++i) s0 += s_red[i];
        ws[blk] = s0;
    }

    unsigned long long* rings = (unsigned long long*)(ws + 320);
    unsigned long long* pub = rings + (size_t)b * RING;   // h==0, w_==7
    unsigned long long* con = rings + (size_t)b * RING;   // h==1, w_==0
    const int kb_pub   = 448;             // 16 * amin(g=7)
    const int kb_con   = 448;
    const int kmax_con = 448 + 1087;      // producer's last diag = 1535

    const float c1 = 7.213475204444817f;     // log2(e)/gamma
    const float c2 = 0.13862943611198906f;   // gamma*ln(2)
    const int amin = g << 2;                 // first abs window = 4g
    const int prodmax = amin + 63;           // producer wave's amax = 4(g-1)+67

    float r1 = FINF;
    float dgp;                               // dg(d) = up(d-1), carried
    unsigned long long pe1 = 0;
    int ppf = 0;
    float hpf1 = 0.f;
    int hpff = 0;
    float hv;

    // ---- pre-loop: stage hvd (diag 64g-2) once, seed dgp ----
    {
        float hvd0;
        if (w_ == 0) {
            if (h == 0) {
                hvd0 = (l == 0) ? 0.0f : FINF;
            } else {
                const int kk2 = (g << 6) - 2 + l;         // 510 + l
                const int id2 = min(kk2 - kb_con, RING - 1);
                const bool n2 = (l < 16) && (kk2 <= kmax_con);
                unsigned long long e2;
                do {
                    e2 = __hip_atomic_load(con + id2, __ATOMIC_RELAXED,
                                           __HIP_MEMORY_SCOPE_AGENT);
                } while (!__all((!n2) | ((int)(e2 >> 32) == kk2)));
                hvd0 = n2 ? __uint_as_float((unsigned)e2) : FINF;
            }
        } else {
            int pv;
            do {
                pv = __hip_atomic_load(&s_prog[w_ - 1], __ATOMIC_ACQUIRE,
                                       __HIP_MEMORY_SCOPE_WORKGROUP);
            } while (pv < amin);
            hvd0 = s_row[w_ - 1][min(62 + l, 1087)];
        }
        dgp = shflup1(hvd0, FINF);           // lane0 <- hvd0[0], others FINF
    }

// ---- hot step: chain with in-chain D load (step i) + D math (step i-2) ----
#define STEPF(i, BA,BB,BY, CA,CB,CY, DCI, DC2, RH) do {                     \
        const float up_ = shflup1(hv, r1);                                  \
        hv = rotdn1(hv);                                                    \
        const int j_ = jb1 + (i);                                           \
        BA = s_c4[3*j_]; BB = s_c4[3*j_+1]; BY = s_c4[3*j_+2].x;            \
        float m_, M_;                                                       \
        asm("v_min3_f32 %0, %1, %2, %3"                                     \
            : "=v"(m_) : "v"(up_), "v"(r1), "v"(dgp));                      \
        asm("v_max3_f32 %0, %1, %2, %3"                                     \
            : "=v"(M_) : "v"(up_), "v"(r1), "v"(dgp));                      \
        const float md_ = __builtin_amdgcn_fmed3f(up_, r1, dgp);            \
        dgp = up_;                                                          \
        const float mc_ = m_ * c1;                                          \
        const float ea_ = __builtin_amdgcn_exp2f(fmaf(md_, -c1, mc_));      \
        const float eb_ = __builtin_amdgcn_exp2f(fmaf(M_,  -c1, mc_));      \
        {   float ac_ = x2 + CY, ac2_ = 0.f;                                \
            ac_  = fmaf(pa.x, CA.x, ac_ );  ac2_ = fmaf(pa.y, CA.y, ac2_);  \
            ac_  = fmaf(pa.z, CA.z, ac_ );  ac2_ = fmaf(pa.w, CA.w, ac2_);  \
            ac_  = fmaf(pb.x, CB.x, ac_ );  ac2_ = fmaf(pb.y, CB.y, ac2_);  \
            ac_  = fmaf(pb.z, CB.z, ac_ );  ac2_ = fmaf(pb.w, CB.w, ac2_);  \
            DC2 = ac_ + ac2_; }                                             \
        const float lg_ = __builtin_amdgcn_logf(1.0f + (ea_ + eb_));        \
        const float rn_ = (DCI) + fmaf(-c2, lg_, m_);                       \
        r1 = rn_; RH = rn_;                                                 \
    } while (0)

// hot step without the i-2 math (steps 0,1)
#define STEPF0(i, BA,BB,BY, DCI, RH) do {                                   \
        const float up_ = shflup1(hv, r1);                                  \
        hv = rotdn1(hv);                                                    \
        const int j_ = jb1 + (i);                                           \
        BA = s_c4[3*j_]; BB = s_c4[3*j_+1]; BY = s_c4[3*j_+2].x;            \
        float m_, M_;                                                       \
        asm("v_min3_f32 %0, %1, %2, %3"                                     \
            : "=v"(m_) : "v"(up_), "v"(r1), "v"(dgp));                      \
        asm("v_max3_f32 %0, %1, %2, %3"                                     \
            : "=v"(M_) : "v"(up_), "v"(r1), "v"(dgp));                      \
        const float md_ = __builtin_amdgcn_fmed3f(up_, r1, dgp);            \
        dgp = up_;                                                          \
        const float mc_ = m_ * c1;                                          \
        const float ea_ = __builtin_amdgcn_exp2f(fmaf(md_, -c1, mc_));      \
        const float eb_ = __builtin_amdgcn_exp2f(fmaf(M_,  -c1, mc_));      \
        const float lg_ = __builtin_amdgcn_logf(1.0f + (ea_ + eb_));        \
        const float rn_ = (DCI) + fmaf(-c2, lg_, m_);                       \
        r1 = rn_; RH = rn_;                                                 \
    } while (0)

// tail math for the last two loads of a hot window
#define DMATHT(CA,CB,CY, DC2) do {                                          \
        float ac_ = x2 + CY, ac2_ = 0.f;                                    \
        ac_  = fmaf(pa.x, CA.x, ac_ );  ac2_ = fmaf(pa.y, CA.y, ac2_);      \
        ac_  = fmaf(pa.z, CA.z, ac_ );  ac2_ = fmaf(pa.w, CA.w, ac2_);      \
        ac_  = fmaf(pb.x, CB.x, ac_ );  ac2_ = fmaf(pb.y, CB.y, ac2_);      \
        ac_  = fmaf(pb.z, CB.z, ac_ );  ac2_ = fmaf(pb.w, CB.w, ac2_);      \
        DC2 = ac_ + ac2_;                                                   \
    } while (0)

// edge step: masked recurrence
#define STEPE(i, DCI, RH) do {                                              \
        const float up_ = shflup1(hv, r1);                                  \
        hv = rotdn1(hv);                                                    \
        float m_, M_;                                                       \
        asm("v_min3_f32 %0, %1, %2, %3"                                     \
            : "=v"(m_) : "v"(up_), "v"(r1), "v"(dgp));                      \
        asm("v_max3_f32 %0, %1, %2, %3"                                     \
            : "=v"(M_) : "v"(up_), "v"(r1), "v"(dgp));                      \
        const float md_ = __builtin_amdgcn_fmed3f(up_, r1, dgp);            \
        dgp = up_;                                                          \
        const float mc_ = m_ * c1;                                          \
        const float ea_ = __builtin_amdgcn_exp2f(fmaf(md_, -c1, mc_));      \
        const float eb_ = __builtin_amdgcn_exp2f(fmaf(M_,  -c1, mc_));      \
        const float lg_ = __builtin_amdgcn_logf(1.0f + (ea_ + eb_));        \
        float rn_ = (DCI) + fmaf(-c2, lg_, m_);                             \
        rn_ = ((unsigned)(jb0 + (i)) < (unsigned)TT) ? rn_ : FINF;          \
        r1 = rn_; RH = rn_;                                                 \
    } while (0)

// clamped D (edge windows / prologue)
#define DCLAMP(JB, i, DC) do {                                              \
        int jc_ = (JB) + (i);                                               \
        jc_ = jc_ < 0 ? 0 : (jc_ > (TT-1) ? (TT-1) : jc_);                  \
        const float4 va_ = s_c4[3*jc_];                                     \
        const float4 vb_ = s_c4[3*jc_+1];                                   \
        const float  yv_ = s_c4[3*jc_+2].x;                                 \
        float ac_ = x2 + yv_, ac2_ = 0.f;                                   \
        ac_  = fmaf(pa.x, va_.x, ac_ );  ac2_ = fmaf(pa.y, va_.y, ac2_);    \
        ac_  = fmaf(pa.z, va_.z, ac_ );  ac2_ = fmaf(pa.w, va_.w, ac2_);    \
        ac_  = fmaf(pb.x, vb_.x, ac_ );  ac2_ = fmaf(pb.y, vb_.y, ac2_);    \
        ac_  = fmaf(pb.z, vb_.z, ac_ );  ac2_ = fmaf(pb.w, vb_.w, ac2_);    \
        DC = ac_ + ac2_;                                                    \
    } while (0)

    // D for window 0 (prologue, clamped)
    float Dc0,Dc1,Dc2,Dc3,Dc4,Dc5,Dc6,Dc7;
    float Dc8,Dc9,Dc10,Dc11,Dc12,Dc13,Dc14,Dc15;
    {
        const int jb = -l;
        DCLAMP(jb, 0,Dc0 ); DCLAMP(jb, 1,Dc1 ); DCLAMP(jb, 2,Dc2 );
        DCLAMP(jb, 3,Dc3 ); DCLAMP(jb, 4,Dc4 ); DCLAMP(jb, 5,Dc5 );
        DCLAMP(jb, 6,Dc6 ); DCLAMP(jb, 7,Dc7 ); DCLAMP(jb, 8,Dc8 );
        DCLAMP(jb, 9,Dc9 ); DCLAMP(jb,10,Dc10); DCLAMP(jb,11,Dc11);
        DCLAMP(jb,12,Dc12); DCLAMP(jb,13,Dc13); DCLAMP(jb,14,Dc14);
        DCLAMP(jb,15,Dc15);
    }
    float rh14_last = FINF;
    float4 vA0, vB0, vA1, vB1, vA2, vB2;
    float  yv0, yv1, yv2;

    for (int u = 0; u <= 67; ++u) {
        const int a  = amin + u;
        const int k0 = a << 4;
        const int jb0 = (u << 4) - l;        // col index of diag k0 at this lane
        const int jb1 = jb0 + 16;            // same for window u+1

        // ---- stage halo hv (diag k0-1) ----
        if (w_ == 0) {
            if (h == 0) {
                hv = FINF;
            } else {
                const int kk1 = k0 - 1 + l;
                const int id1 = min(kk1 - kb_con, RING - 1);
                const bool n1 = (l < 16) && (kk1 <= kmax_con);
                unsigned long long e1;
                if (ppf) { e1 = pe1; ppf = 0; }
                else {
                    e1 = __hip_atomic_load(con + id1, __ATOMIC_RELAXED,
                                           __HIP_MEMORY_SCOPE_AGENT);
                }
                while (!__all((!n1) | ((int)(e1 >> 32) == kk1))) {
                    e1 = __hip_atomic_load(con + id1, __ATOMIC_RELAXED,
                                           __HIP_MEMORY_SCOPE_AGENT);
                }
                hv = n1 ? __uint_as_float((unsigned)e1) : FINF;
            }
        } else {
            if (hpff) { hv = hpf1; hpff = 0; }
            else {
                const int need = (a < prodmax) ? a : prodmax;
                int pv;
                do {
                    pv = __hip_atomic_load(&s_prog[w_ - 1], __ATOMIC_ACQUIRE,
                                           __HIP_MEMORY_SCOPE_WORKGROUP);
                } while (pv < need);
                hv = s_row[w_ - 1][min((u << 4) + 63 + l, 1087)];
            }
        }

        float rh0,rh1,rh2,rh3,rh4,rh5,rh6,rh7;
        float rh8,rh9,rh10,rh11,rh12,rh13,rh14,rh15;

        if (u >= 4 && u <= 62) {
            STEPF0( 0, vA0,vB0,yv0,               Dc0 , rh0 );
            STEPF0( 1, vA1,vB1,yv1,               Dc1 , rh1 );
            STEPF ( 2, vA2,vB2,yv2, vA0,vB0,yv0,  Dc2 , Dc0 , rh2 );
            STEPF ( 3, vA0,vB0,yv0, vA1,vB1,yv1,  Dc3 , Dc1 , rh3 );
            STEPF ( 4, vA1,vB1,yv1, vA2,vB2,yv2,  Dc4 , Dc2 , rh4 );
            STEPF ( 5, vA2,vB2,yv2, vA0,vB0,yv0,  Dc5 , Dc3 , rh5 );
            STEPF ( 6, vA0,vB0,yv0, vA1,vB1,yv1,  Dc6 , Dc4 , rh6 );
            STEPF ( 7, vA1,vB1,yv1, vA2,vB2,yv2,  Dc7 , Dc5 , rh7 );
            STEPF ( 8, vA2,vB2,yv2, vA0,vB0,yv0,  Dc8 , Dc6 , rh8 );
            STEPF ( 9, vA0,vB0,yv0, vA1,vB1,yv1,  Dc9 , Dc7 , rh9 );
            STEPF (10, vA1,vB1,yv1, vA2,vB2,yv2,  Dc10, Dc8 , rh10);
            STEPF (11, vA2,vB2,yv2, vA0,vB0,yv0,  Dc11, Dc9 , rh11);
            STEPF (12, vA0,vB0,yv0, vA1,vB1,yv1,  Dc12, Dc10, rh12);
            STEPF (13, vA1,vB1,yv1, vA2,vB2,yv2,  Dc13, Dc11, rh13);
            STEPF (14, vA2,vB2,yv2, vA0,vB0,yv0,  Dc14, Dc12, rh14);
            STEPF (15, vA0,vB0,yv0, vA1,vB1,yv1,  Dc15, Dc13, rh15);
            DMATHT(vA2,vB2,yv2, Dc14);
            DMATHT(vA0,vB0,yv0, Dc15);
        } else {
            STEPE( 0,Dc0 ,rh0 ); STEPE( 1,Dc1 ,rh1 );
            STEPE( 2,Dc2 ,rh2 ); STEPE( 3,Dc3 ,rh3 );
            STEPE( 4,Dc4 ,rh4 ); STEPE( 5,Dc5 ,rh5 );
            STEPE( 6,Dc6 ,rh6 ); STEPE( 7,Dc7 ,rh7 );
            STEPE( 8,Dc8 ,rh8 ); STEPE( 9,Dc9 ,rh9 );
            STEPE(10,Dc10,rh10); STEPE(11,Dc11,rh11);
            STEPE(12,Dc12,rh12); STEPE(13,Dc13,rh13);
            STEPE(14,Dc14,rh14); STEPE(15,Dc15,rh15);
            if (u < 67) {
                DCLAMP(jb1, 0,Dc0 ); DCLAMP(jb1, 1,Dc1 ); DCLAMP(jb1, 2,Dc2 );
                DCLAMP(jb1, 3,Dc3 ); DCLAMP(jb1, 4,Dc4 ); DCLAMP(jb1, 5,Dc5 );
                DCLAMP(jb1, 6,Dc6 ); DCLAMP(jb1, 7,Dc7 ); DCLAMP(jb1, 8,Dc8 );
                DCLAMP(jb1, 9,Dc9 ); DCLAMP(jb1,10,Dc10); DCLAMP(jb1,11,Dc11);
                DCLAMP(jb1,12,Dc12); DCLAMP(jb1,13,Dc13); DCLAMP(jb1,14,Dc14);
                DCLAMP(jb1,15,Dc15);
            } else {
                rh14_last = rh14;            // diag 2046, row 1023, col 1023
            }
        }

        // bottom-row store
        if (l == 63) {
            float4* dst = (float4*)&s_row[w_][u << 4];
            dst[0] = make_float4(rh0,  rh1,  rh2,  rh3);
            dst[1] = make_float4(rh4,  rh5,  rh6,  rh7);
            dst[2] = make_float4(rh8,  rh9,  rh10, rh11);
            dst[3] = make_float4(rh12, rh13, rh14, rh15);
        }

        // ---- mark window complete for intra-block consumer ----
        if (w_ < 7 && l == 0) {
            __hip_atomic_store(&s_prog[w_], a, __ATOMIC_RELEASE,
                               __HIP_MEMORY_SCOPE_WORKGROUP);
        }
        // ---- producer: publish window as self-validating u64 entries ----
        if (w_ == 7 && h == 0) {
            if (l < 16) {
                const int kk = k0 + l;
                const unsigned long long ev =
                    ((unsigned long long)(unsigned)kk << 32) |
                    (unsigned long long)__float_as_uint(s_row[7][(u << 4) + l]);
                __hip_atomic_store(pub + (kk - kb_pub), ev,
                                   __ATOMIC_RELAXED, __HIP_MEMORY_SCOPE_AGENT);
            }
        }
        // ---- cross-block consumer: prefetch next window's hv entries ----
        if (w_ == 0 && h == 1 && u < 67) {
            const int kk1 = k0 + 15 + l;
            pe1 = __hip_atomic_load(con + min(kk1 - kb_con, RING - 1),
                                    __ATOMIC_RELAXED, __HIP_MEMORY_SCOPE_AGENT);
            ppf = 1;
        }
        // ---- intra-block consumer: prefetch next window's hv if ready ----
        if (w_ != 0 && u < 67) {
            const int neednx = ((a + 1) < prodmax) ? (a + 1) : prodmax;
            const int pv = __hip_atomic_load(&s_prog[w_ - 1], __ATOMIC_ACQUIRE,
                                             __HIP_MEMORY_SCOPE_WORKGROUP);
            if (pv >= neednx) {
                hpf1 = s_row[w_ - 1][min(((u + 1) << 4) + 63 + l, 1087)];
                hpff = 1;
            }
        }
    }
    if (h == 1 && tid == 511) ws[256 + b] = rh14_last;   // r_{2T-2}(T-1)
#undef STEPF
#undef STEPF0
#undef DMATHT
#undef STEPE
#undef DCLAMP
}

__global__ __launch_bounds__(256) void finalize2_kernel(
    const float* __restrict__ ws, float* __restrict__ out)
{
    __shared__ float sm[4], ss[4];
    const int tid = threadIdx.x, l = tid & 63, w = tid >> 6;
    float m  = (tid < 128) ? ws[tid] : 0.f;
    float sd = (tid < 64) ? ws[256 + tid] : 0.f;
    #pragma unroll
    for (int off = 32; off > 0; off >>= 1) {
        m  += __shfl_down(m,  off, 64);
        sd += __shfl_down(sd, off, 64);
    }
    if (l == 0) { sm[w] = m; ss[w] = sd; }
    __syncthreads();
    if (tid == 0) {
        float M = sm[0] + sm[1] + sm[2] + sm[3];
        float S = ss[0] + ss[1] + ss[2] + ss[3];
        out[0] = ALPHA_ * (M / 524288.0f) + (1.0f - ALPHA_) * (S / 64.0f);
    }
}

extern "C" void kernel_launch(void* const* d_in, const int* in_sizes, int n_in,
                              void* d_out, int out_size, void* d_ws, size_t ws_size,
                              hipStream_t stream) {
    const float* pred   = (const float*)d_in[0];
    const float* target = (const float*)d_in[1];
    float* ws  = (float*)d_ws;
    float* out = (float*)d_out;

    sdtw_band_kernel<<<128, 512, 0, stream>>>(pred, target, ws);
    finalize2_kernel<<<1, 256, 0, stream>>>(ws, out);
}

// Round 17
// 306.641 us; speedup vs baseline: 1.2016x; 1.2016x over previous
//
#include <hip/hip_runtime.h>

// CombinedLoss: 0.7*MSE + 0.3*mean_b softDTW_gamma.  B=64, T=1024, C=8, fp32.
// R24 = R19 restored (session best: dispatch 262us, bench 307us, absmax 0).
// FLOOR ANALYSIS (rounds 9-23): critical path = 2047 serial anti-diagonals
// + ~240 diag-equivalents of wave-skew granularity ~= 2288 steps x ~275cy
// (measured, invariant across 10 structural variants) ~= 630k cy = 262us.
// Exonerated by direct experiment: sync mechanism (R9 flat), LDS latency
// (R10/R17/R18 flat), bank conflicts (R14/R15 flat at floor), register
// pressure (R16 regressed), issue count (R19 VALU down / time flat), dual
// in-wave chains (R20 1.5x regress), window size K=32 (R21/R22 flat, F~=0),
// 2 waves/SIMD TLP (R23 1.22x regress).  K=16 is the path-vs-overhead
// optimum.  Remaining cost is the per-diagonal dependent softmin chain
// (DPP -> min3/med3 -> mul/fma -> exp2 -> add -> log2 -> fma -> add) that
// in-order issue cannot overlap from within one wave.
// Structure: fused R(u)||D(u+1) windows (R13, the -32% win), direct per-lane
// LDS D-loads, 48B-stride padded columns (bank floor), dg=up_prev carry
// (exact identity), 3-buffer D-load rotation, 256 blocks x 256 thr,
// 1 wave/SIMD, free-running waves, LDS progress flags intra-block,
// self-validating 8B atomics cross-block.
// ws: [0,256) mse | [256,320) sdtw | u64 rings @ float-offset 320 (~1.6 MB).

constexpr int TT = 1024;
constexpr float ALPHA_ = 0.7f;
constexpr float FINF = 1000000000.0f;
constexpr int RING = 1088;

__device__ __forceinline__ float shflup1(float old0, float v) {
    return __int_as_float(__builtin_amdgcn_update_dpp(
        __float_as_int(old0), __float_as_int(v), 0x138, 0xf, 0xf, false));
}
__device__ __forceinline__ float rotdn1(float v) {
    return __int_as_float(__builtin_amdgcn_update_dpp(
        0, __float_as_int(v), 0x130, 0xf, 0xf, false));
}

__global__ __launch_bounds__(256) void sdtw_band_kernel(
    const float* __restrict__ pred, const float* __restrict__ target,
    float* __restrict__ ws)
{
    // col j: A-half at 3j, B-half at 3j+1, y2 at 3j+2.x (48B stride)
    __shared__ float4 s_c4[TT * 3];
    __shared__ float  s_row[4][1088];    // per-wave bottom row, full length
    __shared__ float  s_red[4];
    __shared__ int    s_prog[4];         // last completed abs window per wave

    const int blk = blockIdx.x;
    const int b   = blk & 63;                  // batch (q*64+b: same-XCD bands)
    const int q   = blk >> 6;                  // band
    const int tid = threadIdx.x;
    const int l   = tid & 63;
    const int w_  = __builtin_amdgcn_readfirstlane(tid >> 6);
    const int g   = (q << 2) + w_;             // global wave 0..15
    const int gbase = g << 6;
    const int row   = gbase + l;

    if (tid < 4) s_prog[tid] = -1;

    const float* pr = pred   + ((size_t)b * TT + row) * 8;
    const float* tr = target + ((size_t)b * TT + row) * 8;
    const float4 pa = ((const float4*)pr)[0];
    const float4 pb = ((const float4*)pr)[1];
    const float4 ma = ((const float4*)tr)[0];
    const float4 mb = ((const float4*)tr)[1];

    float x2 = 0.f, msep = 0.f;
    {
        const float pp[8] = {pa.x,pa.y,pa.z,pa.w,pb.x,pb.y,pb.z,pb.w};
        const float tt[8] = {ma.x,ma.y,ma.z,ma.w,mb.x,mb.y,mb.z,mb.w};
        #pragma unroll
        for (int c = 0; c < 8; ++c) {
            x2 = fmaf(pp[c], pp[c], x2);
            float d = pp[c] - tt[c];
            msep = fmaf(d, d, msep);
        }
    }
    // stage all 1024 columns (4 per thread), padded layout
    const float* tg = target + (size_t)b * TT * 8;
    #pragma unroll
    for (int c0 = 0; c0 < 4; ++c0) {
        const int col = tid + (c0 << 8);
        const float4 u0 = ((const float4*)(tg + (size_t)col * 8))[0];
        const float4 u1 = ((const float4*)(tg + (size_t)col * 8))[1];
        const float y2 = u0.x*u0.x + u0.y*u0.y + u0.z*u0.z + u0.w*u0.w
                       + u1.x*u1.x + u1.y*u1.y + u1.z*u1.z + u1.w*u1.w;
        s_c4[3*col]   = make_float4(-2.f*u0.x, -2.f*u0.y, -2.f*u0.z, -2.f*u0.w);
        s_c4[3*col+1] = make_float4(-2.f*u1.x, -2.f*u1.y, -2.f*u1.z, -2.f*u1.w);
        s_c4[3*col+2] = make_float4(y2, 0.f, 0.f, 0.f);
    }
    #pragma unroll
    for (int off = 32; off > 0; off >>= 1) msep += __shfl_down(msep, off, 64);
    if (l == 0) s_red[w_] = msep;
    __syncthreads();                      // the ONLY block-wide barrier
    if (tid == 0) ws[blk] = s_red[0] + s_red[1] + s_red[2] + s_red[3];

    unsigned long long* rings = (unsigned long long*)(ws + 320);
    unsigned long long* pub = rings + (size_t)(q * 64 + b) * RING;       // w_==3,q<3
    unsigned long long* con = rings + (size_t)((q - 1) * 64 + b) * RING; // w_==0,q>0
    const int kb_pub   = 256 * q + 192;
    const int kb_con   = 256 * q - 64;
    const int kmax_con = kb_con + 1086;

    const float c1 = 7.213475204444817f;     // log2(e)/gamma
    const float c2 = 0.13862943611198906f;   // gamma*ln(2)
    const int amin = g << 2;                 // first abs window = 4g
    const int amax = amin + 67;
    const int prodmax = amin + 63;           // producer wave's amax = 4(g-1)+67

    float r1 = FINF;
    float dgp;                               // dg(d) = up(d-1), carried
    unsigned long long pe1 = 0;
    int ppf = 0;
    float hpf1 = 0.f;
    int hpff = 0;
    float hv;

    // ---- pre-loop: stage hvd for the FIRST window only, seed dgp ----
    {
        float hvd0;
        if (w_ == 0) {
            if (q == 0) {
                hvd0 = (l == 0) ? 0.0f : FINF;
            } else {
                const int kk2 = (amin << 4) - 2 + l;
                const int id2 = min(kk2 - kb_con, RING - 1);
                const bool n2 = (l < 16) && (kk2 <= kmax_con);
                unsigned long long e2;
                do {
                    e2 = __hip_atomic_load(con + id2, __ATOMIC_RELAXED,
                                           __HIP_MEMORY_SCOPE_AGENT);
                } while (!__all((!n2) | ((int)(e2 >> 32) == kk2)));
                hvd0 = n2 ? __uint_as_float((unsigned)e2) : FINF;
            }
        } else {
            const int need0 = (amin < prodmax) ? amin : prodmax;
            int pv;
            do {
                pv = __hip_atomic_load(&s_prog[w_ - 1], __ATOMIC_ACQUIRE,
                                       __HIP_MEMORY_SCOPE_WORKGROUP);
            } while (pv < need0);
            hvd0 = s_row[w_ - 1][min(62 + l, 1087)];
        }
        dgp = shflup1(hvd0, FINF);           // lane0 <- hvd0[0], others FINF
    }

// ---- hot step: chain with in-chain D load (step i) + D math (step i-2) ----
#define STEPF(i, BA,BB,BY, CA,CB,CY, DCI, DC2, RH) do {                     \
        const float up_ = shflup1(hv, r1);                                  \
        hv = rotdn1(hv);                                                    \
        const int j_ = jb1 + (i);                                           \
        BA = s_c4[3*j_]; BB = s_c4[3*j_+1]; BY = s_c4[3*j_+2].x;            \
        float m_, M_;                                                       \
        asm("v_min3_f32 %0, %1, %2, %3"                                     \
            : "=v"(m_) : "v"(up_), "v"(r1), "v"(dgp));                      \
        asm("v_max3_f32 %0, %1, %2, %3"                                     \
            : "=v"(M_) : "v"(up_), "v"(r1), "v"(dgp));                      \
        const float md_ = __builtin_amdgcn_fmed3f(up_, r1, dgp);            \
        dgp = up_;                                                          \
        const float mc_ = m_ * c1;                                          \
        const float ea_ = __builtin_amdgcn_exp2f(fmaf(md_, -c1, mc_));      \
        const float eb_ = __builtin_amdgcn_exp2f(fmaf(M_,  -c1, mc_));      \
        {   float ac_ = x2 + CY, ac2_ = 0.f;                                \
            ac_  = fmaf(pa.x, CA.x, ac_ );  ac2_ = fmaf(pa.y, CA.y, ac2_);  \
            ac_  = fmaf(pa.z, CA.z, ac_ );  ac2_ = fmaf(pa.w, CA.w, ac2_);  \
            ac_  = fmaf(pb.x, CB.x, ac_ );  ac2_ = fmaf(pb.y, CB.y, ac2_);  \
            ac_  = fmaf(pb.z, CB.z, ac_ );  ac2_ = fmaf(pb.w, CB.w, ac2_);  \
            DC2 = ac_ + ac2_; }                                             \
        const float lg_ = __builtin_amdgcn_logf(1.0f + (ea_ + eb_));        \
        const float rn_ = (DCI) + fmaf(-c2, lg_, m_);                       \
        r1 = rn_; RH = rn_;                                                 \
    } while (0)

// hot step without the i-2 math (steps 0,1; their consumers ran in prev tail)
#define STEPF0(i, BA,BB,BY, DCI, RH) do {                                   \
        const float up_ = shflup1(hv, r1);                                  \
        hv = rotdn1(hv);                                                    \
        const int j_ = jb1 + (i);                                           \
        BA = s_c4[3*j_]; BB = s_c4[3*j_+1]; BY = s_c4[3*j_+2].x;            \
        float m_, M_;                                                       \
        asm("v_min3_f32 %0, %1, %2, %3"                                     \
            : "=v"(m_) : "v"(up_), "v"(r1), "v"(dgp));                      \
        asm("v_max3_f32 %0, %1, %2, %3"                                     \
            : "=v"(M_) : "v"(up_), "v"(r1), "v"(dgp));                      \
        const float md_ = __builtin_amdgcn_fmed3f(up_, r1, dgp);            \
        dgp = up_;                                                          \
        const float mc_ = m_ * c1;                                          \
        const float ea_ = __builtin_amdgcn_exp2f(fmaf(md_, -c1, mc_));      \
        const float eb_ = __builtin_amdgcn_exp2f(fmaf(M_,  -c1, mc_));      \
        const float lg_ = __builtin_amdgcn_logf(1.0f + (ea_ + eb_));        \
        const float rn_ = (DCI) + fmaf(-c2, lg_, m_);                       \
        r1 = rn_; RH = rn_;                                                 \
    } while (0)

// tail math for the last two loads of a hot window
#define DMATHT(CA,CB,CY, DC2) do {                                          \
        float ac_ = x2 + CY, ac2_ = 0.f;                                    \
        ac_  = fmaf(pa.x, CA.x, ac_ );  ac2_ = fmaf(pa.y, CA.y, ac2_);      \
        ac_  = fmaf(pa.z, CA.z, ac_ );  ac2_ = fmaf(pa.w, CA.w, ac2_);      \
        ac_  = fmaf(pb.x, CB.x, ac_ );  ac2_ = fmaf(pb.y, CB.y, ac2_);      \
        ac_  = fmaf(pb.z, CB.z, ac_ );  ac2_ = fmaf(pb.w, CB.w, ac2_);      \
        DC2 = ac_ + ac2_;                                                   \
    } while (0)

// edge step: masked recurrence, no load pipeline
#define STEPE(i, DCI, RH) do {                                              \
        const float up_ = shflup1(hv, r1);                                  \
        hv = rotdn1(hv);                                                    \
        float m_, M_;                                                       \
        asm("v_min3_f32 %0, %1, %2, %3"                                     \
            : "=v"(m_) : "v"(up_), "v"(r1), "v"(dgp));                      \
        asm("v_max3_f32 %0, %1, %2, %3"                                     \
            : "=v"(M_) : "v"(up_), "v"(r1), "v"(dgp));                      \
        const float md_ = __builtin_amdgcn_fmed3f(up_, r1, dgp);            \
        dgp = up_;                                                          \
        const float mc_ = m_ * c1;                                          \
        const float ea_ = __builtin_amdgcn_exp2f(fmaf(md_, -c1, mc_));      \
        const float eb_ = __builtin_amdgcn_exp2f(fmaf(M_,  -c1, mc_));      \
        const float lg_ = __builtin_amdgcn_logf(1.0f + (ea_ + eb_));        \
        float rn_ = (DCI) + fmaf(-c2, lg_, m_);                             \
        rn_ = ((unsigned)(jb0 + (i)) < (unsigned)TT) ? rn_ : FINF;          \
        r1 = rn_; RH = rn_;                                                 \
    } while (0)

// clamped D (edge windows / prologue)
#define DCLAMP(JB, i, DC) do {                                              \
        int jc_ = (JB) + (i);                                               \
        jc_ = jc_ < 0 ? 0 : (jc_ > (TT-1) ? (TT-1) : jc_);                  \
        const float4 va_ = s_c4[3*jc_];                                     \
        const float4 vb_ = s_c4[3*jc_+1];                                   \
        const float  yv_ = s_c4[3*jc_+2].x;                                 \
        float ac_ = x2 + yv_, ac2_ = 0.f;                                   \
        ac_  = fmaf(pa.x, va_.x, ac_ );  ac2_ = fmaf(pa.y, va_.y, ac2_);    \
        ac_  = fmaf(pa.z, va_.z, ac_ );  ac2_ = fmaf(pa.w, va_.w, ac2_);    \
        ac_  = fmaf(pb.x, vb_.x, ac_ );  ac2_ = fmaf(pb.y, vb_.y, ac2_);    \
        ac_  = fmaf(pb.z, vb_.z, ac_ );  ac2_ = fmaf(pb.w, vb_.w, ac2_);    \
        DC = ac_ + ac2_;                                                    \
    } while (0)

    // D for window 0 (prologue, clamped)
    float Dc0,Dc1,Dc2,Dc3,Dc4,Dc5,Dc6,Dc7;
    float Dc8,Dc9,Dc10,Dc11,Dc12,Dc13,Dc14,Dc15;
    {
        const int jb = -l;
        DCLAMP(jb, 0,Dc0 ); DCLAMP(jb, 1,Dc1 ); DCLAMP(jb, 2,Dc2 );
        DCLAMP(jb, 3,Dc3 ); DCLAMP(jb, 4,Dc4 ); DCLAMP(jb, 5,Dc5 );
        DCLAMP(jb, 6,Dc6 ); DCLAMP(jb, 7,Dc7 ); DCLAMP(jb, 8,Dc8 );
        DCLAMP(jb, 9,Dc9 ); DCLAMP(jb,10,Dc10); DCLAMP(jb,11,Dc11);
        DCLAMP(jb,12,Dc12); DCLAMP(jb,13,Dc13); DCLAMP(jb,14,Dc14);
        DCLAMP(jb,15,Dc15);
    }
    float rh14_last = FINF;
    float4 vA0, vB0, vA1, vB1, vA2, vB2;
    float  yv0, yv1, yv2;

    for (int u = 0; u <= 67; ++u) {
        const int a  = amin + u;
        const int k0 = a << 4;
        const int jb0 = (u << 4) - l;        // col index of diag k0 at this lane
        const int jb1 = jb0 + 16;            // same for window u+1

        // ---- stage halo hv (diag k0-1) only ----
        if (w_ == 0) {
            if (q == 0) {
                hv = FINF;
            } else {
                const int kk1 = k0 - 1 + l;
                const int id1 = min(kk1 - kb_con, RING - 1);
                const bool n1 = (l < 16) && (kk1 <= kmax_con);
                unsigned long long e1;
                if (ppf) { e1 = pe1; ppf = 0; }
                else {
                    e1 = __hip_atomic_load(con + id1, __ATOMIC_RELAXED,
                                           __HIP_MEMORY_SCOPE_AGENT);
                }
                while (!__all((!n1) | ((int)(e1 >> 32) == kk1))) {
                    e1 = __hip_atomic_load(con + id1, __ATOMIC_RELAXED,
                                           __HIP_MEMORY_SCOPE_AGENT);
                }
                hv = n1 ? __uint_as_float((unsigned)e1) : FINF;
            }
        } else {
            if (hpff) { hv = hpf1; hpff = 0; }
            else {
                const int need = (a < prodmax) ? a : prodmax;
                int pv;
                do {
                    pv = __hip_atomic_load(&s_prog[w_ - 1], __ATOMIC_ACQUIRE,
                                           __HIP_MEMORY_SCOPE_WORKGROUP);
                } while (pv < need);
                hv = s_row[w_ - 1][min((u << 4) + 63 + l, 1087)];
            }
        }

        float rh0,rh1,rh2,rh3,rh4,rh5,rh6,rh7;
        float rh8,rh9,rh10,rh11,rh12,rh13,rh14,rh15;

        if (u >= 4 && u <= 62) {
            STEPF0( 0, vA0,vB0,yv0,               Dc0 , rh0 );
            STEPF0( 1, vA1,vB1,yv1,               Dc1 , rh1 );
            STEPF ( 2, vA2,vB2,yv2, vA0,vB0,yv0,  Dc2 , Dc0 , rh2 );
            STEPF ( 3, vA0,vB0,yv0, vA1,vB1,yv1,  Dc3 , Dc1 , rh3 );
            STEPF ( 4, vA1,vB1,yv1, vA2,vB2,yv2,  Dc4 , Dc2 , rh4 );
            STEPF ( 5, vA2,vB2,yv2, vA0,vB0,yv0,  Dc5 , Dc3 , rh5 );
            STEPF ( 6, vA0,vB0,yv0, vA1,vB1,yv1,  Dc6 , Dc4 , rh6 );
            STEPF ( 7, vA1,vB1,yv1, vA2,vB2,yv2,  Dc7 , Dc5 , rh7 );
            STEPF ( 8, vA2,vB2,yv2, vA0,vB0,yv0,  Dc8 , Dc6 , rh8 );
            STEPF ( 9, vA0,vB0,yv0, vA1,vB1,yv1,  Dc9 , Dc7 , rh9 );
            STEPF (10, vA1,vB1,yv1, vA2,vB2,yv2,  Dc10, Dc8 , rh10);
            STEPF (11, vA2,vB2,yv2, vA0,vB0,yv0,  Dc11, Dc9 , rh11);
            STEPF (12, vA0,vB0,yv0, vA1,vB1,yv1,  Dc12, Dc10, rh12);
            STEPF (13, vA1,vB1,yv1, vA2,vB2,yv2,  Dc13, Dc11, rh13);
            STEPF (14, vA2,vB2,yv2, vA0,vB0,yv0,  Dc14, Dc12, rh14);
            STEPF (15, vA0,vB0,yv0, vA1,vB1,yv1,  Dc15, Dc13, rh15);
            DMATHT(vA2,vB2,yv2, Dc14);
            DMATHT(vA0,vB0,yv0, Dc15);
        } else {
            STEPE( 0,Dc0 ,rh0 ); STEPE( 1,Dc1 ,rh1 );
            STEPE( 2,Dc2 ,rh2 ); STEPE( 3,Dc3 ,rh3 );
            STEPE( 4,Dc4 ,rh4 ); STEPE( 5,Dc5 ,rh5 );
            STEPE( 6,Dc6 ,rh6 ); STEPE( 7,Dc7 ,rh7 );
            STEPE( 8,Dc8 ,rh8 ); STEPE( 9,Dc9 ,rh9 );
            STEPE(10,Dc10,rh10); STEPE(11,Dc11,rh11);
            STEPE(12,Dc12,rh12); STEPE(13,Dc13,rh13);
            STEPE(14,Dc14,rh14); STEPE(15,Dc15,rh15);
            if (u < 67) {
                DCLAMP(jb1, 0,Dc0 ); DCLAMP(jb1, 1,Dc1 ); DCLAMP(jb1, 2,Dc2 );
                DCLAMP(jb1, 3,Dc3 ); DCLAMP(jb1, 4,Dc4 ); DCLAMP(jb1, 5,Dc5 );
                DCLAMP(jb1, 6,Dc6 ); DCLAMP(jb1, 7,Dc7 ); DCLAMP(jb1, 8,Dc8 );
                DCLAMP(jb1, 9,Dc9 ); DCLAMP(jb1,10,Dc10); DCLAMP(jb1,11,Dc11);
                DCLAMP(jb1,12,Dc12); DCLAMP(jb1,13,Dc13); DCLAMP(jb1,14,Dc14);
                DCLAMP(jb1,15,Dc15);
            } else {
                rh14_last = rh14;            // diag 2046, row 1023, col 1023
            }
        }

        // bottom-row store (packed; masked FINF entries are correct values)
        if (l == 63) {
            float4* dst = (float4*)&s_row[w_][u << 4];
            dst[0] = make_float4(rh0,  rh1,  rh2,  rh3);
            dst[1] = make_float4(rh4,  rh5,  rh6,  rh7);
            dst[2] = make_float4(rh8,  rh9,  rh10, rh11);
            dst[3] = make_float4(rh12, rh13, rh14, rh15);
        }

        // ---- mark window complete for intra-block consumer ----
        if (w_ < 3 && l == 0) {
            __hip_atomic_store(&s_prog[w_], a, __ATOMIC_RELEASE,
                               __HIP_MEMORY_SCOPE_WORKGROUP);
        }
        // ---- producer: publish window as self-validating u64 entries ----
        if (w_ == 3 && q < 3) {
            if (l < 16) {
                const int kk = k0 + l;
                const unsigned long long ev =
                    ((unsigned long long)(unsigned)kk << 32) |
                    (unsigned long long)__float_as_uint(s_row[3][(u << 4) + l]);
                __hip_atomic_store(pub + (kk - kb_pub), ev,
                                   __ATOMIC_RELAXED, __HIP_MEMORY_SCOPE_AGENT);
            }
        }
        // ---- cross-block consumer: prefetch next window's hv entries ----
        if (w_ == 0 && q > 0 && a < amax) {
            const int kk1 = k0 + 15 + l;
            pe1 = __hip_atomic_load(con + min(kk1 - kb_con, RING - 1),
                                    __ATOMIC_RELAXED, __HIP_MEMORY_SCOPE_AGENT);
            ppf = 1;
        }
        // ---- intra-block consumer: prefetch next window's hv if ready ----
        if (w_ != 0 && a < amax) {
            const int neednx = ((a + 1) < prodmax) ? (a + 1) : prodmax;
            const int pv = __hip_atomic_load(&s_prog[w_ - 1], __ATOMIC_ACQUIRE,
                                             __HIP_MEMORY_SCOPE_WORKGROUP);
            if (pv >= neednx) {
                hpf1 = s_row[w_ - 1][min(((u + 1) << 4) + 63 + l, 1087)];
                hpff = 1;
            }
        }
    }
    if (q == 3 && tid == 255) ws[256 + b] = rh14_last;   // r_{2T-2}(T-1)
#undef STEPF
#undef STEPF0
#undef DMATHT
#undef STEPE
#undef DCLAMP
}

__global__ __launch_bounds__(256) void finalize2_kernel(
    const float* __restrict__ ws, float* __restrict__ out)
{
    __shared__ float sm[4], ss[4];
    const int tid = threadIdx.x, l = tid & 63, w = tid >> 6;
    float m  = ws[tid];
    float sd = (tid < 64) ? ws[256 + tid] : 0.f;
    #pragma unroll
    for (int off = 32; off > 0; off >>= 1) {
        m  += __shfl_down(m,  off, 64);
        sd += __shfl_down(sd, off, 64);
    }
    if (l == 0) { sm[w] = m; ss[w] = sd; }
    __syncthreads();
    if (tid == 0) {
        float M = sm[0] + sm[1] + sm[2] + sm[3];
        float S = ss[0] + ss[1] + ss[2] + ss[3];
        out[0] = ALPHA_ * (M / 524288.0f) + (1.0f - ALPHA_) * (S / 64.0f);
    }
}

extern "C" void kernel_launch(void* const* d_in, const int* in_sizes, int n_in,
                              void* d_out, int out_size, void* d_ws, size_t ws_size,
                              hipStream_t stream) {
    const float* pred   = (const float*)d_in[0];
    const float* target = (const float*)d_in[1];
    float* ws  = (float*)d_ws;
    float* out = (float*)d_out;

    sdtw_band_kernel<<<256, 256, 0, stream>>>(pred, target, ws);
    finalize2_kernel<<<1, 256, 0, stream>>>(ws, out);
}